// Round 1
// baseline (328.845 us; speedup 1.0000x reference)
//
#include <hip/hip_runtime.h>

// B=8192 rows, D=2048 cols, 6 fp32 input arrays, fp32 output of B elements.
// out[b] = ab / sqrt(aa*bb) where
//   rot_r = hr*rr - hi*ri ; rot_i = -(hi*rr + hr*ri)
//   ab = sum(rot_r*tr + rot_i*ti); aa = sum(rot_r^2 + rot_i^2); bb = sum(tr^2 + ti^2)

#define BLOCK 256
#define DCOLS 2048

__global__ __launch_bounds__(BLOCK) void chrono_rot_kernel(
    const float* __restrict__ hr, const float* __restrict__ hi,
    const float* __restrict__ rr, const float* __restrict__ ri,
    const float* __restrict__ tr, const float* __restrict__ ti,
    float* __restrict__ out)
{
    const int row = blockIdx.x;
    const int t   = threadIdx.x;
    const size_t base = (size_t)row * DCOLS;

    const float4* hr4 = (const float4*)(hr + base);
    const float4* hi4 = (const float4*)(hi + base);
    const float4* rr4 = (const float4*)(rr + base);
    const float4* ri4 = (const float4*)(ri + base);
    const float4* tr4 = (const float4*)(tr + base);
    const float4* ti4 = (const float4*)(ti + base);

    float s_ab = 0.f, s_aa = 0.f, s_bb = 0.f;

    // D/4 = 512 float4 per array; 256 threads -> 2 iterations, coalesced.
    #pragma unroll
    for (int it = 0; it < DCOLS / (BLOCK * 4); ++it) {
        const int i = it * BLOCK + t;
        const float4 a = hr4[i];
        const float4 b = hi4[i];
        const float4 c = rr4[i];
        const float4 d = ri4[i];
        const float4 e = tr4[i];
        const float4 f = ti4[i];

        #pragma unroll
        for (int j = 0; j < 4; ++j) {
            const float av = (&a.x)[j], bv = (&b.x)[j];
            const float cv = (&c.x)[j], dv = (&d.x)[j];
            const float ev = (&e.x)[j], fv = (&f.x)[j];
            const float rot_r = av * cv - bv * dv;
            const float rot_i = -(bv * cv + av * dv);
            s_ab += rot_r * ev + rot_i * fv;
            s_aa += rot_r * rot_r + rot_i * rot_i;
            s_bb += ev * ev + fv * fv;
        }
    }

    // Wave-64 shuffle reduction
    #pragma unroll
    for (int off = 32; off > 0; off >>= 1) {
        s_ab += __shfl_down(s_ab, off, 64);
        s_aa += __shfl_down(s_aa, off, 64);
        s_bb += __shfl_down(s_bb, off, 64);
    }

    // Cross-wave reduction via LDS (4 waves per block)
    __shared__ float red[3][BLOCK / 64];
    const int wave = t >> 6;
    const int lane = t & 63;
    if (lane == 0) {
        red[0][wave] = s_ab;
        red[1][wave] = s_aa;
        red[2][wave] = s_bb;
    }
    __syncthreads();
    if (t == 0) {
        float ab = 0.f, aa = 0.f, bb = 0.f;
        #pragma unroll
        for (int w = 0; w < BLOCK / 64; ++w) {
            ab += red[0][w];
            aa += red[1][w];
            bb += red[2][w];
        }
        out[row] = ab / sqrtf(aa * bb);
    }
}

extern "C" void kernel_launch(void* const* d_in, const int* in_sizes, int n_in,
                              void* d_out, int out_size, void* d_ws, size_t ws_size,
                              hipStream_t stream) {
    const float* hr = (const float*)d_in[0];
    const float* hi = (const float*)d_in[1];
    const float* rr = (const float*)d_in[2];
    const float* ri = (const float*)d_in[3];
    const float* tr = (const float*)d_in[4];
    const float* ti = (const float*)d_in[5];
    float* out = (float*)d_out;

    const int B = out_size; // 8192 rows
    chrono_rot_kernel<<<B, BLOCK, 0, stream>>>(hr, hi, rr, ri, tr, ti, out);
}